// Round 18
// baseline (382.973 us; speedup 1.0000x reference)
//
#include <hip/hip_runtime.h>
#include <hip/hip_bf16.h>

#define HID 2048
#define NH 20
#define QR 768
#define KVR 512
#define DN 192
#define DR 64
#define DV 256
#define HD 256          // HEAD_DIM = DN + DR
#define S_LEN 2048
#define HKV 448         // DN + DV
#define KV_N (NH * HKV) // 8960
#define Q_N (NH * HD)   // 5120
#define O_N (NH * DV)   // 5120
#define KVA_N (KVR + DR) // 576
#define KVAP 640         // padded kv_a rows
#define QKVA (QR + KVAP) // 1408 fused a-proj cols

typedef short bf16x8 __attribute__((ext_vector_type(8)));
typedef short bf16x4 __attribute__((ext_vector_type(4)));
typedef float f32x4 __attribute__((ext_vector_type(4)));

__device__ inline short f2bs(float f) {
  __hip_bfloat16 h = __float2bfloat16(f);
  return *reinterpret_cast<short*>(&h);
}
__device__ inline float bs2f(short s) {
  __hip_bfloat16 h = *reinterpret_cast<__hip_bfloat16*>(&s);
  return __bfloat162float(h);
}

__device__ inline void gload16(const void* g, void* l) {
  __builtin_amdgcn_global_load_lds((const __attribute__((address_space(1))) void*)g,
                                   (__attribute__((address_space(3))) void*)l, 16, 0, 0);
}

#define WAIT_VM0() asm volatile("s_waitcnt vmcnt(0)" ::: "memory")

// ---------------- batched fp32 -> bf16 convert: all 6 tensors in ONE launch ----------------
#define C_X   (S_LEN * HID / 8)
#define C_QAW (QR * HID / 8)
#define C_KAW (KVA_N * HID / 8)
#define C_QBW (Q_N * QR / 8)
#define C_KBW (KV_N * KVR / 8)
#define C_OW  (HID * O_N / 8)
#define FB0 C_X
#define FB1 (FB0 + C_QAW)
#define FB2 (FB1 + C_KAW)
#define FB3 (FB2 + C_QBW)
#define FB4 (FB3 + C_KBW)
#define FB5 (FB4 + C_OW)
__global__ void f2b_multi(const float* __restrict__ x, const float* __restrict__ qaw,
                          const float* __restrict__ kaw, const float* __restrict__ qbw,
                          const float* __restrict__ kbw, const float* __restrict__ ow,
                          short* __restrict__ xb, short* __restrict__ wcat_q,
                          short* __restrict__ wcat_k, short* __restrict__ qbwb,
                          short* __restrict__ kbwb, short* __restrict__ owb) {
  for (size_t i = (size_t)blockIdx.x * blockDim.x + threadIdx.x; i < FB5;
       i += (size_t)gridDim.x * blockDim.x) {
    const float* src;
    short* dst;
    size_t j;
    if (i < FB0)      { src = x;   dst = xb;     j = i; }
    else if (i < FB1) { src = qaw; dst = wcat_q; j = i - FB0; }
    else if (i < FB2) { src = kaw; dst = wcat_k; j = i - FB1; }
    else if (i < FB3) { src = qbw; dst = qbwb;   j = i - FB2; }
    else if (i < FB4) { src = kbw; dst = kbwb;   j = i - FB3; }
    else              { src = ow;  dst = owb;    j = i - FB4; }
    f32x4 a = *(const f32x4*)(src + j * 8);
    f32x4 b = *(const f32x4*)(src + j * 8 + 4);
    bf16x8 r;
    r[0] = f2bs(a[0]); r[1] = f2bs(a[1]); r[2] = f2bs(a[2]); r[3] = f2bs(a[3]);
    r[4] = f2bs(b[0]); r[5] = f2bs(b[1]); r[6] = f2bs(b[2]); r[7] = f2bs(b[3]);
    *(bf16x8*)(dst + j * 8) = r;
  }
}

// ---------------- big GEMM: 128x128 tile, BK=64, global_load_lds + XOR swizzle ----------------
template <int OUT_BF16>
__global__ __launch_bounds__(256) void gemm128(const short* __restrict__ A,
                                               const short* __restrict__ B,
                                               void* __restrict__ Cp,
                                               int M, int N, int K) {
  __shared__ alignas(16) short As[128 * 64];
  __shared__ alignas(16) short Bs[128 * 64];
  int tid = threadIdx.x;
  int w = tid >> 6, l = tid & 63;
  int lr = l & 15, lg = l >> 4;
  int wr = w >> 1, wc = w & 1;
  int row0 = blockIdx.y * 128, col0 = blockIdx.x * 128;
  f32x4 acc[4][4] = {};
  for (int k0 = 0; k0 < K; k0 += 64) {
    if (k0) __syncthreads();
#pragma unroll
    for (int p = 0; p < 4; ++p) {
      int c = p * 256 + tid;
      int row = c >> 3;
      int sb = ((c & 7) * 16) ^ ((row & 7) << 4);
      gload16((const char*)A + ((size_t)(row0 + row) * K + k0) * 2 + sb, (char*)As + c * 16);
      gload16((const char*)B + ((size_t)(col0 + row) * K + k0) * 2 + sb, (char*)Bs + c * 16);
    }
    __syncthreads();
    bf16x8 af[4][2], bf[4][2];
#pragma unroll
    for (int m = 0; m < 4; ++m)
#pragma unroll
      for (int kk = 0; kk < 2; ++kk) {
        int ra = wr * 64 + m * 16 + lr;
        int rb = wc * 64 + m * 16 + lr;
        int cb = kk * 64 + lg * 16;
        af[m][kk] = *(const bf16x8*)((const char*)As + ra * 128 + (cb ^ ((ra & 7) << 4)));
        bf[m][kk] = *(const bf16x8*)((const char*)Bs + rb * 128 + (cb ^ ((rb & 7) << 4)));
      }
#pragma unroll
    for (int m = 0; m < 4; ++m)
#pragma unroll
      for (int n = 0; n < 4; ++n) {
        acc[m][n] = __builtin_amdgcn_mfma_f32_16x16x32_bf16(af[m][0], bf[n][0], acc[m][n], 0, 0, 0);
        acc[m][n] = __builtin_amdgcn_mfma_f32_16x16x32_bf16(af[m][1], bf[n][1], acc[m][n], 0, 0, 0);
      }
  }
#pragma unroll
  for (int m = 0; m < 4; ++m)
#pragma unroll
    for (int n = 0; n < 4; ++n)
#pragma unroll
      for (int r = 0; r < 4; ++r) {
        int row = row0 + wr * 64 + m * 16 + lg * 4 + r;
        int col = col0 + wc * 64 + n * 16 + lr;
        if (OUT_BF16)
          ((short*)Cp)[(size_t)row * N + col] = f2bs(acc[m][n][r]);
        else
          ((float*)Cp)[(size_t)row * N + col] = acc[m][n][r];
      }
}

// ---------------- fused dual up-projection GEMM: q_b (640 blocks) + kv_b (1120 blocks) ----------------
__global__ __launch_bounds__(256) void gemm128_dual(const short* __restrict__ Aq,
                                                    const short* __restrict__ Bq,
                                                    short* __restrict__ Cq,
                                                    const short* __restrict__ Akv,
                                                    const short* __restrict__ Bkv,
                                                    short* __restrict__ Ckv) {
  const short *A, *B;
  short* C;
  int N, K, bx, by;
  int b = blockIdx.x;
  if (b < 640) {
    A = Aq; B = Bq; C = Cq; N = Q_N; K = QR;
    bx = b % 40; by = b / 40;
  } else {
    int b2 = b - 640;
    A = Akv; B = Bkv; C = Ckv; N = KV_N; K = KVR;
    bx = b2 % 70; by = b2 / 70;
  }
  __shared__ alignas(16) short As[128 * 64];
  __shared__ alignas(16) short Bs[128 * 64];
  int tid = threadIdx.x;
  int w = tid >> 6, l = tid & 63;
  int lr = l & 15, lg = l >> 4;
  int wr = w >> 1, wc = w & 1;
  int row0 = by * 128, col0 = bx * 128;
  f32x4 acc[4][4] = {};
  for (int k0 = 0; k0 < K; k0 += 64) {
    if (k0) __syncthreads();
#pragma unroll
    for (int p = 0; p < 4; ++p) {
      int c = p * 256 + tid;
      int row = c >> 3;
      int sb = ((c & 7) * 16) ^ ((row & 7) << 4);
      gload16((const char*)A + ((size_t)(row0 + row) * K + k0) * 2 + sb, (char*)As + c * 16);
      gload16((const char*)B + ((size_t)(col0 + row) * K + k0) * 2 + sb, (char*)Bs + c * 16);
    }
    __syncthreads();
    bf16x8 af[4][2], bf[4][2];
#pragma unroll
    for (int m = 0; m < 4; ++m)
#pragma unroll
      for (int kk = 0; kk < 2; ++kk) {
        int ra = wr * 64 + m * 16 + lr;
        int rb = wc * 64 + m * 16 + lr;
        int cb = kk * 64 + lg * 16;
        af[m][kk] = *(const bf16x8*)((const char*)As + ra * 128 + (cb ^ ((ra & 7) << 4)));
        bf[m][kk] = *(const bf16x8*)((const char*)Bs + rb * 128 + (cb ^ ((rb & 7) << 4)));
      }
#pragma unroll
    for (int m = 0; m < 4; ++m)
#pragma unroll
      for (int n = 0; n < 4; ++n) {
        acc[m][n] = __builtin_amdgcn_mfma_f32_16x16x32_bf16(af[m][0], bf[n][0], acc[m][n], 0, 0, 0);
        acc[m][n] = __builtin_amdgcn_mfma_f32_16x16x32_bf16(af[m][1], bf[n][1], acc[m][n], 0, 0, 0);
      }
  }
#pragma unroll
  for (int m = 0; m < 4; ++m)
#pragma unroll
    for (int n = 0; n < 4; ++n)
#pragma unroll
      for (int r = 0; r < 4; ++r) {
        int row = row0 + wr * 64 + m * 16 + lg * 4 + r;
        int col = col0 + wc * 64 + n * 16 + lr;
        C[(size_t)row * N + col] = f2bs(acc[m][n][r]);
      }
}

// ---------------- medium GEMM: 64x128 tile (a-proj only) ----------------
__global__ __launch_bounds__(256) void gemm64(const short* __restrict__ A,
                                              const short* __restrict__ B,
                                              float* __restrict__ C,
                                              int M, int N, int K) {
  __shared__ alignas(16) short As[64 * 64];    // 8KB
  __shared__ alignas(16) short Bs[128 * 64];   // 16KB
  int tid = threadIdx.x;
  int w = tid >> 6, l = tid & 63;
  int lr = l & 15, lg = l >> 4;
  int wr = w >> 1, wc = w & 1;
  int row0 = blockIdx.y * 64, col0 = blockIdx.x * 128;
  f32x4 acc[2][4] = {};
  for (int k0 = 0; k0 < K; k0 += 64) {
    if (k0) __syncthreads();
#pragma unroll
    for (int p = 0; p < 2; ++p) {
      int c = p * 256 + tid;
      int row = c >> 3;
      int sb = ((c & 7) * 16) ^ ((row & 7) << 4);
      gload16((const char*)A + ((size_t)(row0 + row) * K + k0) * 2 + sb, (char*)As + c * 16);
    }
#pragma unroll
    for (int p = 0; p < 4; ++p) {
      int c = p * 256 + tid;
      int row = c >> 3;
      int sb = ((c & 7) * 16) ^ ((row & 7) << 4);
      gload16((const char*)B + ((size_t)(col0 + row) * K + k0) * 2 + sb, (char*)Bs + c * 16);
    }
    __syncthreads();
    bf16x8 af[2][2], bf[4][2];
#pragma unroll
    for (int m = 0; m < 2; ++m)
#pragma unroll
      for (int kk = 0; kk < 2; ++kk) {
        int ra = wr * 32 + m * 16 + lr;
        int cb = kk * 64 + lg * 16;
        af[m][kk] = *(const bf16x8*)((const char*)As + ra * 128 + (cb ^ ((ra & 7) << 4)));
      }
#pragma unroll
    for (int n = 0; n < 4; ++n)
#pragma unroll
      for (int kk = 0; kk < 2; ++kk) {
        int rb = wc * 64 + n * 16 + lr;
        int cb = kk * 64 + lg * 16;
        bf[n][kk] = *(const bf16x8*)((const char*)Bs + rb * 128 + (cb ^ ((rb & 7) << 4)));
      }
#pragma unroll
    for (int m = 0; m < 2; ++m)
#pragma unroll
      for (int n = 0; n < 4; ++n) {
        acc[m][n] = __builtin_amdgcn_mfma_f32_16x16x32_bf16(af[m][0], bf[n][0], acc[m][n], 0, 0, 0);
        acc[m][n] = __builtin_amdgcn_mfma_f32_16x16x32_bf16(af[m][1], bf[n][1], acc[m][n], 0, 0, 0);
      }
  }
#pragma unroll
  for (int m = 0; m < 2; ++m)
#pragma unroll
    for (int n = 0; n < 4; ++n)
#pragma unroll
      for (int r = 0; r < 4; ++r) {
        int row = row0 + wr * 32 + m * 16 + lg * 4 + r;
        int col = col0 + wc * 64 + n * 16 + lr;
        C[(size_t)row * N + col] = acc[m][n][r];
      }
}

// ---------------- fused double rmsnorm ----------------
__global__ __launch_bounds__(256) void rmsnorm2_kernel(const float* __restrict__ qkv,
                                                       const float* __restrict__ qw,
                                                       const float* __restrict__ kw,
                                                       short* __restrict__ qo,
                                                       short* __restrict__ ko) {
  int row = blockIdx.x;
  __shared__ float red[4];
  {
    const float* x = qkv + (size_t)row * QKVA;
    float ss = 0.f;
    for (int i = threadIdx.x * 4; i < QR; i += 1024) {
      f32x4 v = *(const f32x4*)(x + i);
      ss += v[0] * v[0] + v[1] * v[1] + v[2] * v[2] + v[3] * v[3];
    }
#pragma unroll
    for (int off = 32; off >= 1; off >>= 1) ss += __shfl_down(ss, off);
    if ((threadIdx.x & 63) == 0) red[threadIdx.x >> 6] = ss;
    __syncthreads();
    float sc = rsqrtf((red[0] + red[1] + red[2] + red[3]) / (float)QR + 1e-5f);
    short* o = qo + (size_t)row * QR;
    for (int i = threadIdx.x * 4; i < QR; i += 1024) {
      f32x4 v = *(const f32x4*)(x + i);
      f32x4 g = *(const f32x4*)(qw + i);
      bf16x4 r;
      r[0] = f2bs(v[0] * sc * g[0]); r[1] = f2bs(v[1] * sc * g[1]);
      r[2] = f2bs(v[2] * sc * g[2]); r[3] = f2bs(v[3] * sc * g[3]);
      *(bf16x4*)(o + i) = r;
    }
    __syncthreads();
  }
  {
    const float* x = qkv + (size_t)row * QKVA + QR;
    float ss = 0.f;
    for (int i = threadIdx.x * 4; i < KVR; i += 1024) {
      f32x4 v = *(const f32x4*)(x + i);
      ss += v[0] * v[0] + v[1] * v[1] + v[2] * v[2] + v[3] * v[3];
    }
#pragma unroll
    for (int off = 32; off >= 1; off >>= 1) ss += __shfl_down(ss, off);
    if ((threadIdx.x & 63) == 0) red[threadIdx.x >> 6] = ss;
    __syncthreads();
    float sc = rsqrtf((red[0] + red[1] + red[2] + red[3]) / (float)KVR + 1e-5f);
    short* o = ko + (size_t)row * KVR;
    for (int i = threadIdx.x * 4; i < KVR; i += 1024) {
      f32x4 v = *(const f32x4*)(x + i);
      f32x4 g = *(const f32x4*)(kw + i);
      bf16x4 r;
      r[0] = f2bs(v[0] * sc * g[0]); r[1] = f2bs(v[1] * sc * g[1]);
      r[2] = f2bs(v[2] * sc * g[2]); r[3] = f2bs(v[3] * sc * g[3]);
      *(bf16x4*)(o + i) = r;
    }
  }
}

// ---------------- rope tables ----------------
__global__ void rope_table_kernel(const int* __restrict__ pos, float* __restrict__ ct,
                                  float* __restrict__ st) {
  int s = blockIdx.x * blockDim.x + threadIdx.x;
  if (s >= S_LEN) return;
  double p = (double)pos[s];
  for (int d = 0; d < 32; ++d) {
    double invf = exp(-((double)(2 * d) / 64.0) * log(1.0e6));
    double a = p * invf;
    ct[s * 32 + d] = (float)cos(a);
    st[s * 32 + d] = (float)sin(a);
  }
}

// ---------------- fused rope: blocks 0..159 -> q (in-place), 160..167 -> k_rope ----------------
__global__ void rope_fused_kernel(short* __restrict__ q, const float* __restrict__ qkv,
                                  const float* __restrict__ ct, const float* __restrict__ st,
                                  short* __restrict__ kr) {
  if (blockIdx.x < 160) {
    int idx = blockIdx.x * 256 + threadIdx.x;
    int s = idx / NH, h = idx % NH;
    short* p = q + (size_t)s * Q_N + h * HD + DN;
    bf16x8 v[8];
#pragma unroll
    for (int j = 0; j < 8; ++j) v[j] = *(const bf16x8*)(p + j * 8);
    float x[64];
#pragma unroll
    for (int j = 0; j < 8; ++j)
#pragma unroll
      for (int k = 0; k < 8; ++k) x[j * 8 + k] = bs2f(v[j][k]);
    const float* c = ct + s * 32;
    const float* sn = st + s * 32;
    bf16x8 o[8];
#pragma unroll
    for (int d = 0; d < 32; ++d) {
      float cd = c[d], sd = sn[d];
      float x1 = x[2 * d], x2 = x[2 * d + 1];
      o[d >> 3][d & 7] = f2bs(x1 * cd - x2 * sd);
      o[4 + (d >> 3)][d & 7] = f2bs(x1 * sd + x2 * cd);
    }
#pragma unroll
    for (int j = 0; j < 8; ++j) *(bf16x8*)(p + j * 8) = o[j];
  } else {
    int s = (blockIdx.x - 160) * 256 + threadIdx.x;
    const float* xp = qkv + (size_t)s * QKVA + QR + KVR;
    float x[64];
#pragma unroll
    for (int j = 0; j < 16; ++j) {
      f32x4 v = *(const f32x4*)(xp + j * 4);
      x[j * 4] = v[0]; x[j * 4 + 1] = v[1]; x[j * 4 + 2] = v[2]; x[j * 4 + 3] = v[3];
    }
    const float* c = ct + s * 32;
    const float* sn = st + s * 32;
    bf16x8 o[8];
#pragma unroll
    for (int d = 0; d < 32; ++d) {
      float cd = c[d], sd = sn[d];
      float x1 = x[2 * d], x2 = x[2 * d + 1];
      o[d >> 3][d & 7] = f2bs(x1 * cd - x2 * sd);
      o[4 + (d >> 3)][d & 7] = f2bs(x1 * sd + x2 * cd);
    }
    short* kp = kr + s * 64;
#pragma unroll
    for (int j = 0; j < 8; ++j) *(bf16x8*)(kp + j * 8) = o[j];
  }
}

// ---------------- fused K-rearrange + V-transpose ----------------
__global__ __launch_bounds__(256) void kv_prep(const short* __restrict__ kvx,
                                               const short* __restrict__ kr,
                                               short* __restrict__ kc,
                                               short* __restrict__ vtg) {
  if (blockIdx.x < 5120) {
    int idx = blockIdx.x * 256 + threadIdx.x;
    int h = idx >> 16;
    int r = idx & 65535;
    int s = r >> 5, c = r & 31;
    const short* src = (c < 24) ? kvx + (size_t)s * KV_N + h * HKV + c * 8
                                : kr + (size_t)s * 64 + (c - 24) * 8;
    *(bf16x8*)(kc + ((size_t)h * S_LEN + s) * HD + c * 8) = *(const bf16x8*)src;
  } else {
    __shared__ short tile[64][65];
    int b = blockIdx.x - 5120;
    int s0 = (b & 31) * 64, d0 = ((b >> 5) & 3) * 64, h = b >> 7;
    int tid = threadIdx.x;
#pragma unroll
    for (int p = 0; p < 2; ++p) {
      int s = p * 32 + (tid >> 3), dc = (tid & 7) * 8;
      bf16x8 v = *(const bf16x8*)(kvx + (size_t)(s0 + s) * KV_N + h * HKV + DN + d0 + dc);
#pragma unroll
      for (int j = 0; j < 8; ++j) tile[s][dc + j] = v[j];
    }
    __syncthreads();
#pragma unroll
    for (int p = 0; p < 2; ++p) {
      int d = p * 32 + (tid >> 3), sc = (tid & 7) * 8;
      bf16x4 a, bb;
#pragma unroll
      for (int j = 0; j < 4; ++j) a[j] = tile[sc + j][d];
#pragma unroll
      for (int j = 0; j < 4; ++j) bb[j] = tile[sc + 4 + j][d];
      int q1 = sc & 31, q2 = q1 + 4;
      int p1 = (q1 < 16) ? (q1 >> 2) * 8 : ((q1 - 16) >> 2) * 8 + 4;
      int p2 = (q2 < 16) ? (q2 >> 2) * 8 : ((q2 - 16) >> 2) * 8 + 4;
      int s = ((d & 15) >> 1) & 3;
      p1 = ((((p1 >> 3) ^ s)) << 3) | (p1 & 7);
      p2 = ((((p2 >> 3) ^ s)) << 3) | (p2 & 7);
      size_t rowbase = ((size_t)h * DV + d0 + d) * S_LEN + s0 + (sc & ~31);
      *(bf16x4*)(vtg + rowbase + p1) = a;
      *(bf16x4*)(vtg + rowbase + p2) = bb;
    }
  }
}

// ---------------- fused flash attention v10 (proven 160us config, unchanged) ----------------
__global__ __launch_bounds__(256, 2) void attn10(const short* __restrict__ q,
                                                 const short* __restrict__ kc,
                                                 const short* __restrict__ vtg,
                                                 short* __restrict__ out) {
  __shared__ alignas(16) short ks[2][32 * 256];  // 32KB, 512B rows, 3-bit src XOR
  __shared__ alignas(16) short vt[2][256 * 32];  // 32KB, vt[d][key-perm], 64B rows
  int bid = blockIdx.x;
  int swz = (bid & 7) * 40 + (bid >> 3);         // 320 = 8*40, bijective
  int h = swz >> 4, qblk = swz & 15;
  int tid = threadIdx.x;
  int w = tid >> 6, l = tid & 63;
  int lr = l & 15, lg = l >> 4;

  const char* kch = (const char*)(kc + (size_t)h * S_LEN * HD);
  const short* vth = vtg + (size_t)h * DV * S_LEN;

  int qrowA = qblk * 128 + w * 32 + lr;
  const short* qbA = q + (size_t)qrowA * Q_N + h * HD;
  const short* qbB = qbA + (size_t)16 * Q_N;
  bf16x8 qfA[8], qfB[8];
#pragma unroll
  for (int kk = 0; kk < 8; ++kk) {
    bf16x8 va = *(const bf16x8*)(qbA + kk * 32 + lg * 8);
    bf16x8 vb = *(const bf16x8*)(qbB + kk * 32 + lg * 8);
#pragma unroll
    for (int j = 0; j < 8; ++j) {
      va[j] = f2bs(bs2f(va[j]) * 0.0625f);
      vb[j] = f2bs(bs2f(vb[j]) * 0.0625f);
    }
    qfA[kk] = va;
    qfB[kk] = vb;
  }

  f32x4 accA[16] = {}, accB[16] = {};
  float mA = -3e38f, mB = -3e38f;
  float lsA = 0.f, lsB = 0.f;

  auto stage_k = [&](int buf, int key0) {
#pragma unroll
    for (int p = 0; p < 4; ++p) {
      int c = p * 256 + tid;
      int row = c >> 5;
      int sb = ((c & 31) * 16) ^ ((row & 7) << 4);
      gload16(kch + (size_t)(key0 + row) * 512 + sb, (char*)ks[buf] + c * 16);
    }
  };
  auto stage_v = [&](int buf, int key0) {
#pragma unroll
    for (int p = 0; p < 4; ++p) {
      int c = p * 256 + tid;
      int d = c >> 2, slot = c & 3;
      gload16(vth + (size_t)d * S_LEN + key0 + slot * 8, (char*)vt[buf] + c * 16);
    }
  };

  stage_k(0, 0);
  stage_v(0, 0);
  WAIT_VM0();
  __builtin_amdgcn_s_barrier();

  int sxor = (lr >> 1) & 3;

  for (int kb = 0; kb < S_LEN / 32; ++kb) {
    int cur = kb & 1;
    int key0 = kb * 32;
    if (kb + 1 < S_LEN / 32) {
      stage_k(cur ^ 1, key0 + 32);
      stage_v(cur ^ 1, key0 + 32);
    }

    f32x4 s0A = {}, s1A = {}, s0B = {}, s1B = {};
    __builtin_amdgcn_s_setprio(1);
#pragma unroll
    for (int kk = 0; kk < 8; ++kk) {
      int cb = kk * 64 + lg * 16;
      int sw = (lr & 7) << 4;
      bf16x8 k0 = *(const bf16x8*)((const char*)ks[cur] + lr * 512 + (cb ^ sw));
      bf16x8 k1 = *(const bf16x8*)((const char*)ks[cur] + (16 + lr) * 512 + (cb ^ sw));
      s0A = __builtin_amdgcn_mfma_f32_16x16x32_bf16(k0, qfA[kk], s0A, 0, 0, 0);
      s1A = __builtin_amdgcn_mfma_f32_16x16x32_bf16(k1, qfA[kk], s1A, 0, 0, 0);
      s0B = __builtin_amdgcn_mfma_f32_16x16x32_bf16(k0, qfB[kk], s0B, 0, 0, 0);
      s1B = __builtin_amdgcn_mfma_f32_16x16x32_bf16(k1, qfB[kk], s1B, 0, 0, 0);
    }
    __builtin_amdgcn_s_setprio(0);

    bf16x8 paA, paB;
    {
      float mx = fmaxf(fmaxf(fmaxf(s0A[0], s0A[1]), fmaxf(s0A[2], s0A[3])),
                       fmaxf(fmaxf(s1A[0], s1A[1]), fmaxf(s1A[2], s1A[3])));
      mx = fmaxf(mx, __shfl_xor(mx, 16));
      mx = fmaxf(mx, __shfl_xor(mx, 32));
      bool grow = mx > mA + 8.f;
      if (__any((int)grow)) {
        float mn = fmaxf(mA, mx);
        float co = __expf(mA - mn);
        mA = mn;
        lsA *= co;
        float c0 = __shfl(co, (l & 48) | (lg * 4 + 0));
        float c1 = __shfl(co, (l & 48) | (lg * 4 + 1));
        float c2 = __shfl(co, (l & 48) | (lg * 4 + 2));
        float c3 = __shfl(co, (l & 48) | (lg * 4 + 3));
#pragma unroll
        for (int t = 0; t < 16; ++t) {
          accA[t][0] *= c0; accA[t][1] *= c1; accA[t][2] *= c2; accA[t][3] *= c3;
        }
      }
      float e0 = __expf(s0A[0] - mA), e1 = __expf(s0A[1] - mA);
      float e2 = __expf(s0A[2] - mA), e3 = __expf(s0A[3] - mA);
      float e4 = __expf(s1A[0] - mA), e5 = __expf(s1A[1] - mA);
      float e6 = __expf(s1A[2] - mA), e7 = __expf(s1A[3] - mA);
      float ts = ((e0 + e1) + (e2 + e3)) + ((e4 + e5) + (e6 + e7));
      ts += __shfl_xor(ts, 16);
      ts += __shfl_xor(ts, 32);
      lsA += ts;
      paA[0] = f2bs(e0); paA[1] = f2bs(e1); paA[2] = f2bs(e2); paA[3] = f2bs(e3);
      paA[4] = f2bs(e4); paA[5] = f2bs(e5); paA[6] = f2bs(e6); paA[7] = f2bs(e7);
    }
    {
      float mx = fmaxf(fmaxf(fmaxf(s0B[0], s0B[1]), fmaxf(s0B[2], s0B[3])),
                       fmaxf(fmaxf(s1B[0], s1B[1]), fmaxf(s1B[2], s1B[3])));
      mx = fmaxf(mx, __shfl_xor(mx, 16));
      mx = fmaxf(mx, __shfl_xor(mx, 32));
      bool grow = mx > mB + 8.f;
      if (__any((int)grow)) {
        float mn = fmaxf(mB, mx);
        float co = __expf(mB - mn);
        mB = mn;
        lsB *= co;
        float c0 = __shfl(co, (l & 48) | (lg * 4 + 0));
        float c1 = __shfl(co, (l & 48) | (lg * 4 + 1));
        float c2 = __shfl(co, (l & 48) | (lg * 4 + 2));
        float c3 = __shfl(co, (l & 48) | (lg * 4 + 3));
#pragma unroll
        for (int t = 0; t < 16; ++t) {
          accB[t][0] *= c0; accB[t][1] *= c1; accB[t][2] *= c2; accB[t][3] *= c3;
        }
      }
      float e0 = __expf(s0B[0] - mB), e1 = __expf(s0B[1] - mB);
      float e2 = __expf(s0B[2] - mB), e3 = __expf(s0B[3] - mB);
      float e4 = __expf(s1B[0] - mB), e5 = __expf(s1B[1] - mB);
      float e6 = __expf(s1B[2] - mB), e7 = __expf(s1B[3] - mB);
      float ts = ((e0 + e1) + (e2 + e3)) + ((e4 + e5) + (e6 + e7));
      ts += __shfl_xor(ts, 16);
      ts += __shfl_xor(ts, 32);
      lsB += ts;
      paB[0] = f2bs(e0); paB[1] = f2bs(e1); paB[2] = f2bs(e2); paB[3] = f2bs(e3);
      paB[4] = f2bs(e4); paB[5] = f2bs(e5); paB[6] = f2bs(e6); paB[7] = f2bs(e7);
    }

    __builtin_amdgcn_s_setprio(1);
#pragma unroll
    for (int t = 0; t < 16; ++t) {
      int d = t * 16 + lr;
      bf16x8 vf = *(const bf16x8*)((const char*)vt[cur] + d * 64 + ((lg ^ sxor) << 4));
      accA[t] = __builtin_amdgcn_mfma_f32_16x16x32_bf16(paA, vf, accA[t], 0, 0, 0);
      accB[t] = __builtin_amdgcn_mfma_f32_16x16x32_bf16(paB, vf, accB[t], 0, 0, 0);
    }
    __builtin_amdgcn_s_setprio(0);

    WAIT_VM0();
    __builtin_amdgcn_s_barrier();
  }

  {
    float inv = 1.f / lsA;
    float i0 = __shfl(inv, (l & 48) | (lg * 4 + 0));
    float i1 = __shfl(inv, (l & 48) | (lg * 4 + 1));
    float i2 = __shfl(inv, (l & 48) | (lg * 4 + 2));
    float i3 = __shfl(inv, (l & 48) | (lg * 4 + 3));
#pragma unroll
    for (int t = 0; t < 16; ++t) {
      int row = qblk * 128 + w * 32 + lg * 4;
      int col = h * DV + t * 16 + lr;
      out[(size_t)(row + 0) * O_N + col] = f2bs(accA[t][0] * i0);
      out[(size_t)(row + 1) * O_N + col] = f2bs(accA[t][1] * i1);
      out[(size_t)(row + 2) * O_N + col] = f2bs(accA[t][2] * i2);
      out[(size_t)(row + 3) * O_N + col] = f2bs(accA[t][3] * i3);
    }
  }
  {
    float inv = 1.f / lsB;
    float i0 = __shfl(inv, (l & 48) | (lg * 4 + 0));
    float i1 = __shfl(inv, (l & 48) | (lg * 4 + 1));
    float i2 = __shfl(inv, (l & 48) | (lg * 4 + 2));
    float i3 = __shfl(inv, (l & 48) | (lg * 4 + 3));
#pragma unroll
    for (int t = 0; t < 16; ++t) {
      int row = qblk * 128 + w * 32 + 16 + lg * 4;
      int col = h * DV + t * 16 + lr;
      out[(size_t)(row + 0) * O_N + col] = f2bs(accB[t][0] * i0);
      out[(size_t)(row + 1) * O_N + col] = f2bs(accB[t][1] * i1);
      out[(size_t)(row + 2) * O_N + col] = f2bs(accB[t][2] * i2);
      out[(size_t)(row + 3) * O_N + col] = f2bs(accB[t][3] * i3);
    }
  }
}

extern "C" void kernel_launch(void* const* d_in, const int* in_sizes, int n_in,
                              void* d_out, int out_size, void* d_ws, size_t ws_size,
                              hipStream_t stream) {
  const float* x       = (const float*)d_in[0];
  const int*   pos     = (const int*)d_in[1];
  const float* q_a_w   = (const float*)d_in[2];
  const float* q_b_w   = (const float*)d_in[3];
  const float* kv_a_w  = (const float*)d_in[4];
  const float* kv_b_w  = (const float*)d_in[5];
  const float* o_w     = (const float*)d_in[6];
  const float* q_a_ln  = (const float*)d_in[7];
  const float* kv_a_ln = (const float*)d_in[8];
  float* out = (float*)d_out;

  char* p = (char*)d_ws;
  auto alloc = [&](size_t bytes) {
    char* r = p;
    p += (bytes + 255) & ~(size_t)255;
    return r;
  };
  short* xb    = (short*)alloc((size_t)S_LEN * HID * 2);
  short* wcat  = (short*)alloc((size_t)QKVA * HID * 2);
  short* qbw   = (short*)alloc((size_t)Q_N * QR * 2);
  short* kvbw  = (short*)alloc((size_t)KV_N * KVR * 2);
  short* ow    = (short*)alloc((size_t)HID * O_N * 2);
  float* qkv   = (float*)alloc((size_t)S_LEN * QKVA * 4);
  short* q_ln  = (short*)alloc((size_t)S_LEN * QR * 2);
  short* qbuf  = (short*)alloc((size_t)S_LEN * Q_N * 2);
  short* kv_ln = (short*)alloc((size_t)S_LEN * KVR * 2);
  short* kvx   = (short*)alloc((size_t)S_LEN * KV_N * 2);
  short* kr    = (short*)alloc((size_t)S_LEN * 64 * 2);
  float* ct    = (float*)alloc((size_t)S_LEN * 32 * 4);
  float* st    = (float*)alloc((size_t)S_LEN * 32 * 4);
  short* ao    = (short*)alloc((size_t)S_LEN * O_N * 2);
  short* kcb   = (short*)alloc((size_t)NH * S_LEN * HD * 2);
  short* vtg   = (short*)alloc((size_t)NH * DV * S_LEN * 2);
  (void)ws_size; (void)n_in; (void)in_sizes; (void)out_size;

  dim3 blk(256);
  f2b_multi<<<dim3(2048), blk, 0, stream>>>(x, q_a_w, kv_a_w, q_b_w, kv_b_w, o_w,
                                            xb, wcat, wcat + (size_t)QR * HID,
                                            qbw, kvbw, ow);
  (void)hipMemsetAsync(wcat + (size_t)(QR + KVA_N) * HID, 0,
                       (size_t)(KVAP - KVA_N) * HID * 2, stream);

  gemm64<<<dim3(QKVA / 128, S_LEN / 64), blk, 0, stream>>>(xb, wcat, qkv, S_LEN, QKVA, HID);
  rmsnorm2_kernel<<<dim3(S_LEN), blk, 0, stream>>>(qkv, q_a_ln, kv_a_ln, q_ln, kv_ln);
  // fused up-projections: q_b (640 blocks) + kv_b (1120 blocks) in ONE dispatch
  gemm128_dual<<<dim3(1760), blk, 0, stream>>>(q_ln, qbw, qbuf, kv_ln, kvbw, kvx);
  rope_table_kernel<<<dim3(S_LEN / 256), blk, 0, stream>>>(pos, ct, st);
  rope_fused_kernel<<<dim3(168), blk, 0, stream>>>(qbuf, qkv, ct, st, kr);
  kv_prep<<<dim3(7680), blk, 0, stream>>>(kvx, kr, kcb, vtg);
  attn10<<<dim3(NH * S_LEN / 128), blk, 0, stream>>>(qbuf, kcb, vtg, ao);
  // output projection: 128x128 tile, 256 blocks = exactly 1/CU (was gemm64: half MFMA density)
  gemm128<0><<<dim3(HID / 128, S_LEN / 128), blk, 0, stream>>>(ao, ow, out, S_LEN, HID, O_N);
}

// Round 19
// 369.944 us; speedup vs baseline: 1.0352x; 1.0352x over previous
//
#include <hip/hip_runtime.h>
#include <hip/hip_bf16.h>

#define HID 2048
#define NH 20
#define QR 768
#define KVR 512
#define DN 192
#define DR 64
#define DV 256
#define HD 256          // HEAD_DIM = DN + DR
#define S_LEN 2048
#define HKV 448         // DN + DV
#define KV_N (NH * HKV) // 8960
#define Q_N (NH * HD)   // 5120
#define O_N (NH * DV)   // 5120
#define KVA_N (KVR + DR) // 576
#define KVAP 640         // padded kv_a rows
#define QKVA (QR + KVAP) // 1408 fused a-proj cols

typedef short bf16x8 __attribute__((ext_vector_type(8)));
typedef short bf16x4 __attribute__((ext_vector_type(4)));
typedef float f32x4 __attribute__((ext_vector_type(4)));

__device__ inline short f2bs(float f) {
  __hip_bfloat16 h = __float2bfloat16(f);
  return *reinterpret_cast<short*>(&h);
}
__device__ inline float bs2f(short s) {
  __hip_bfloat16 h = *reinterpret_cast<__hip_bfloat16*>(&s);
  return __bfloat162float(h);
}

__device__ inline void gload16(const void* g, void* l) {
  __builtin_amdgcn_global_load_lds((const __attribute__((address_space(1))) void*)g,
                                   (__attribute__((address_space(3))) void*)l, 16, 0, 0);
}

#define WAIT_VM0() asm volatile("s_waitcnt vmcnt(0)" ::: "memory")

// ---------------- batched fp32 -> bf16 convert: all 6 tensors in ONE launch ----------------
#define C_X   (S_LEN * HID / 8)
#define C_QAW (QR * HID / 8)
#define C_KAW (KVA_N * HID / 8)
#define C_QBW (Q_N * QR / 8)
#define C_KBW (KV_N * KVR / 8)
#define C_OW  (HID * O_N / 8)
#define FB0 C_X
#define FB1 (FB0 + C_QAW)
#define FB2 (FB1 + C_KAW)
#define FB3 (FB2 + C_QBW)
#define FB4 (FB3 + C_KBW)
#define FB5 (FB4 + C_OW)
__global__ void f2b_multi(const float* __restrict__ x, const float* __restrict__ qaw,
                          const float* __restrict__ kaw, const float* __restrict__ qbw,
                          const float* __restrict__ kbw, const float* __restrict__ ow,
                          short* __restrict__ xb, short* __restrict__ wcat_q,
                          short* __restrict__ wcat_k, short* __restrict__ qbwb,
                          short* __restrict__ kbwb, short* __restrict__ owb) {
  for (size_t i = (size_t)blockIdx.x * blockDim.x + threadIdx.x; i < FB5;
       i += (size_t)gridDim.x * blockDim.x) {
    const float* src;
    short* dst;
    size_t j;
    if (i < FB0)      { src = x;   dst = xb;     j = i; }
    else if (i < FB1) { src = qaw; dst = wcat_q; j = i - FB0; }
    else if (i < FB2) { src = kaw; dst = wcat_k; j = i - FB1; }
    else if (i < FB3) { src = qbw; dst = qbwb;   j = i - FB2; }
    else if (i < FB4) { src = kbw; dst = kbwb;   j = i - FB3; }
    else              { src = ow;  dst = owb;    j = i - FB4; }
    f32x4 a = *(const f32x4*)(src + j * 8);
    f32x4 b = *(const f32x4*)(src + j * 8 + 4);
    bf16x8 r;
    r[0] = f2bs(a[0]); r[1] = f2bs(a[1]); r[2] = f2bs(a[2]); r[3] = f2bs(a[3]);
    r[4] = f2bs(b[0]); r[5] = f2bs(b[1]); r[6] = f2bs(b[2]); r[7] = f2bs(b[3]);
    *(bf16x8*)(dst + j * 8) = r;
  }
}

// ---------------- fused dual up-projection GEMM: q_b (640 blocks) + kv_b (1120 blocks) ----------------
__global__ __launch_bounds__(256) void gemm128_dual(const short* __restrict__ Aq,
                                                    const short* __restrict__ Bq,
                                                    short* __restrict__ Cq,
                                                    const short* __restrict__ Akv,
                                                    const short* __restrict__ Bkv,
                                                    short* __restrict__ Ckv) {
  const short *A, *B;
  short* C;
  int N, K, bx, by;
  int b = blockIdx.x;
  if (b < 640) {
    A = Aq; B = Bq; C = Cq; N = Q_N; K = QR;
    bx = b % 40; by = b / 40;
  } else {
    int b2 = b - 640;
    A = Akv; B = Bkv; C = Ckv; N = KV_N; K = KVR;
    bx = b2 % 70; by = b2 / 70;
  }
  __shared__ alignas(16) short As[128 * 64];
  __shared__ alignas(16) short Bs[128 * 64];
  int tid = threadIdx.x;
  int w = tid >> 6, l = tid & 63;
  int lr = l & 15, lg = l >> 4;
  int wr = w >> 1, wc = w & 1;
  int row0 = by * 128, col0 = bx * 128;
  f32x4 acc[4][4] = {};
  for (int k0 = 0; k0 < K; k0 += 64) {
    if (k0) __syncthreads();
#pragma unroll
    for (int p = 0; p < 4; ++p) {
      int c = p * 256 + tid;
      int row = c >> 3;
      int sb = ((c & 7) * 16) ^ ((row & 7) << 4);
      gload16((const char*)A + ((size_t)(row0 + row) * K + k0) * 2 + sb, (char*)As + c * 16);
      gload16((const char*)B + ((size_t)(col0 + row) * K + k0) * 2 + sb, (char*)Bs + c * 16);
    }
    __syncthreads();
    bf16x8 af[4][2], bf[4][2];
#pragma unroll
    for (int m = 0; m < 4; ++m)
#pragma unroll
      for (int kk = 0; kk < 2; ++kk) {
        int ra = wr * 64 + m * 16 + lr;
        int rb = wc * 64 + m * 16 + lr;
        int cb = kk * 64 + lg * 16;
        af[m][kk] = *(const bf16x8*)((const char*)As + ra * 128 + (cb ^ ((ra & 7) << 4)));
        bf[m][kk] = *(const bf16x8*)((const char*)Bs + rb * 128 + (cb ^ ((rb & 7) << 4)));
      }
#pragma unroll
    for (int m = 0; m < 4; ++m)
#pragma unroll
      for (int n = 0; n < 4; ++n) {
        acc[m][n] = __builtin_amdgcn_mfma_f32_16x16x32_bf16(af[m][0], bf[n][0], acc[m][n], 0, 0, 0);
        acc[m][n] = __builtin_amdgcn_mfma_f32_16x16x32_bf16(af[m][1], bf[n][1], acc[m][n], 0, 0, 0);
      }
  }
#pragma unroll
  for (int m = 0; m < 4; ++m)
#pragma unroll
    for (int n = 0; n < 4; ++n)
#pragma unroll
      for (int r = 0; r < 4; ++r) {
        int row = row0 + wr * 64 + m * 16 + lg * 4 + r;
        int col = col0 + wc * 64 + n * 16 + lr;
        C[(size_t)row * N + col] = f2bs(acc[m][n][r]);
      }
}

// ---------------- medium GEMM: 64x128 tile (a-proj + out-proj) ----------------
__global__ __launch_bounds__(256) void gemm64(const short* __restrict__ A,
                                              const short* __restrict__ B,
                                              float* __restrict__ C,
                                              int M, int N, int K) {
  __shared__ alignas(16) short As[64 * 64];    // 8KB
  __shared__ alignas(16) short Bs[128 * 64];   // 16KB
  int tid = threadIdx.x;
  int w = tid >> 6, l = tid & 63;
  int lr = l & 15, lg = l >> 4;
  int wr = w >> 1, wc = w & 1;
  int row0 = blockIdx.y * 64, col0 = blockIdx.x * 128;
  f32x4 acc[2][4] = {};
  for (int k0 = 0; k0 < K; k0 += 64) {
    if (k0) __syncthreads();
#pragma unroll
    for (int p = 0; p < 2; ++p) {
      int c = p * 256 + tid;
      int row = c >> 3;
      int sb = ((c & 7) * 16) ^ ((row & 7) << 4);
      gload16((const char*)A + ((size_t)(row0 + row) * K + k0) * 2 + sb, (char*)As + c * 16);
    }
#pragma unroll
    for (int p = 0; p < 4; ++p) {
      int c = p * 256 + tid;
      int row = c >> 3;
      int sb = ((c & 7) * 16) ^ ((row & 7) << 4);
      gload16((const char*)B + ((size_t)(col0 + row) * K + k0) * 2 + sb, (char*)Bs + c * 16);
    }
    __syncthreads();
    bf16x8 af[2][2], bf[4][2];
#pragma unroll
    for (int m = 0; m < 2; ++m)
#pragma unroll
      for (int kk = 0; kk < 2; ++kk) {
        int ra = wr * 32 + m * 16 + lr;
        int cb = kk * 64 + lg * 16;
        af[m][kk] = *(const bf16x8*)((const char*)As + ra * 128 + (cb ^ ((ra & 7) << 4)));
      }
#pragma unroll
    for (int n = 0; n < 4; ++n)
#pragma unroll
      for (int kk = 0; kk < 2; ++kk) {
        int rb = wc * 64 + n * 16 + lr;
        int cb = kk * 64 + lg * 16;
        bf[n][kk] = *(const bf16x8*)((const char*)Bs + rb * 128 + (cb ^ ((rb & 7) << 4)));
      }
#pragma unroll
    for (int m = 0; m < 2; ++m)
#pragma unroll
      for (int n = 0; n < 4; ++n) {
        acc[m][n] = __builtin_amdgcn_mfma_f32_16x16x32_bf16(af[m][0], bf[n][0], acc[m][n], 0, 0, 0);
        acc[m][n] = __builtin_amdgcn_mfma_f32_16x16x32_bf16(af[m][1], bf[n][1], acc[m][n], 0, 0, 0);
      }
  }
#pragma unroll
  for (int m = 0; m < 2; ++m)
#pragma unroll
    for (int n = 0; n < 4; ++n)
#pragma unroll
      for (int r = 0; r < 4; ++r) {
        int row = row0 + wr * 32 + m * 16 + lg * 4 + r;
        int col = col0 + wc * 64 + n * 16 + lr;
        C[(size_t)row * N + col] = acc[m][n][r];
      }
}

// ---------------- fused double rmsnorm ----------------
__global__ __launch_bounds__(256) void rmsnorm2_kernel(const float* __restrict__ qkv,
                                                       const float* __restrict__ qw,
                                                       const float* __restrict__ kw,
                                                       short* __restrict__ qo,
                                                       short* __restrict__ ko) {
  int row = blockIdx.x;
  __shared__ float red[4];
  {
    const float* x = qkv + (size_t)row * QKVA;
    float ss = 0.f;
    for (int i = threadIdx.x * 4; i < QR; i += 1024) {
      f32x4 v = *(const f32x4*)(x + i);
      ss += v[0] * v[0] + v[1] * v[1] + v[2] * v[2] + v[3] * v[3];
    }
#pragma unroll
    for (int off = 32; off >= 1; off >>= 1) ss += __shfl_down(ss, off);
    if ((threadIdx.x & 63) == 0) red[threadIdx.x >> 6] = ss;
    __syncthreads();
    float sc = rsqrtf((red[0] + red[1] + red[2] + red[3]) / (float)QR + 1e-5f);
    short* o = qo + (size_t)row * QR;
    for (int i = threadIdx.x * 4; i < QR; i += 1024) {
      f32x4 v = *(const f32x4*)(x + i);
      f32x4 g = *(const f32x4*)(qw + i);
      bf16x4 r;
      r[0] = f2bs(v[0] * sc * g[0]); r[1] = f2bs(v[1] * sc * g[1]);
      r[2] = f2bs(v[2] * sc * g[2]); r[3] = f2bs(v[3] * sc * g[3]);
      *(bf16x4*)(o + i) = r;
    }
    __syncthreads();
  }
  {
    const float* x = qkv + (size_t)row * QKVA + QR;
    float ss = 0.f;
    for (int i = threadIdx.x * 4; i < KVR; i += 1024) {
      f32x4 v = *(const f32x4*)(x + i);
      ss += v[0] * v[0] + v[1] * v[1] + v[2] * v[2] + v[3] * v[3];
    }
#pragma unroll
    for (int off = 32; off >= 1; off >>= 1) ss += __shfl_down(ss, off);
    if ((threadIdx.x & 63) == 0) red[threadIdx.x >> 6] = ss;
    __syncthreads();
    float sc = rsqrtf((red[0] + red[1] + red[2] + red[3]) / (float)KVR + 1e-5f);
    short* o = ko + (size_t)row * KVR;
    for (int i = threadIdx.x * 4; i < KVR; i += 1024) {
      f32x4 v = *(const f32x4*)(x + i);
      f32x4 g = *(const f32x4*)(kw + i);
      bf16x4 r;
      r[0] = f2bs(v[0] * sc * g[0]); r[1] = f2bs(v[1] * sc * g[1]);
      r[2] = f2bs(v[2] * sc * g[2]); r[3] = f2bs(v[3] * sc * g[3]);
      *(bf16x4*)(o + i) = r;
    }
  }
}

// ---------------- rope tables ----------------
__global__ void rope_table_kernel(const int* __restrict__ pos, float* __restrict__ ct,
                                  float* __restrict__ st) {
  int s = blockIdx.x * blockDim.x + threadIdx.x;
  if (s >= S_LEN) return;
  double p = (double)pos[s];
  for (int d = 0; d < 32; ++d) {
    double invf = exp(-((double)(2 * d) / 64.0) * log(1.0e6));
    double a = p * invf;
    ct[s * 32 + d] = (float)cos(a);
    st[s * 32 + d] = (float)sin(a);
  }
}

// ---------------- fused rope: blocks 0..159 -> q (in-place), 160..167 -> k_rope ----------------
__global__ void rope_fused_kernel(short* __restrict__ q, const float* __restrict__ qkv,
                                  const float* __restrict__ ct, const float* __restrict__ st,
                                  short* __restrict__ kr) {
  if (blockIdx.x < 160) {
    int idx = blockIdx.x * 256 + threadIdx.x;
    int s = idx / NH, h = idx % NH;
    short* p = q + (size_t)s * Q_N + h * HD + DN;
    bf16x8 v[8];
#pragma unroll
    for (int j = 0; j < 8; ++j) v[j] = *(const bf16x8*)(p + j * 8);
    float x[64];
#pragma unroll
    for (int j = 0; j < 8; ++j)
#pragma unroll
      for (int k = 0; k < 8; ++k) x[j * 8 + k] = bs2f(v[j][k]);
    const float* c = ct + s * 32;
    const float* sn = st + s * 32;
    bf16x8 o[8];
#pragma unroll
    for (int d = 0; d < 32; ++d) {
      float cd = c[d], sd = sn[d];
      float x1 = x[2 * d], x2 = x[2 * d + 1];
      o[d >> 3][d & 7] = f2bs(x1 * cd - x2 * sd);
      o[4 + (d >> 3)][d & 7] = f2bs(x1 * sd + x2 * cd);
    }
#pragma unroll
    for (int j = 0; j < 8; ++j) *(bf16x8*)(p + j * 8) = o[j];
  } else {
    int s = (blockIdx.x - 160) * 256 + threadIdx.x;
    const float* xp = qkv + (size_t)s * QKVA + QR + KVR;
    float x[64];
#pragma unroll
    for (int j = 0; j < 16; ++j) {
      f32x4 v = *(const f32x4*)(xp + j * 4);
      x[j * 4] = v[0]; x[j * 4 + 1] = v[1]; x[j * 4 + 2] = v[2]; x[j * 4 + 3] = v[3];
    }
    const float* c = ct + s * 32;
    const float* sn = st + s * 32;
    bf16x8 o[8];
#pragma unroll
    for (int d = 0; d < 32; ++d) {
      float cd = c[d], sd = sn[d];
      float x1 = x[2 * d], x2 = x[2 * d + 1];
      o[d >> 3][d & 7] = f2bs(x1 * cd - x2 * sd);
      o[4 + (d >> 3)][d & 7] = f2bs(x1 * sd + x2 * cd);
    }
    short* kp = kr + s * 64;
#pragma unroll
    for (int j = 0; j < 8; ++j) *(bf16x8*)(kp + j * 8) = o[j];
  }
}

// ---------------- fused K-rearrange + V-transpose ----------------
__global__ __launch_bounds__(256) void kv_prep(const short* __restrict__ kvx,
                                               const short* __restrict__ kr,
                                               short* __restrict__ kc,
                                               short* __restrict__ vtg) {
  if (blockIdx.x < 5120) {
    int idx = blockIdx.x * 256 + threadIdx.x;
    int h = idx >> 16;
    int r = idx & 65535;
    int s = r >> 5, c = r & 31;
    const short* src = (c < 24) ? kvx + (size_t)s * KV_N + h * HKV + c * 8
                                : kr + (size_t)s * 64 + (c - 24) * 8;
    *(bf16x8*)(kc + ((size_t)h * S_LEN + s) * HD + c * 8) = *(const bf16x8*)src;
  } else {
    __shared__ short tile[64][65];
    int b = blockIdx.x - 5120;
    int s0 = (b & 31) * 64, d0 = ((b >> 5) & 3) * 64, h = b >> 7;
    int tid = threadIdx.x;
#pragma unroll
    for (int p = 0; p < 2; ++p) {
      int s = p * 32 + (tid >> 3), dc = (tid & 7) * 8;
      bf16x8 v = *(const bf16x8*)(kvx + (size_t)(s0 + s) * KV_N + h * HKV + DN + d0 + dc);
#pragma unroll
      for (int j = 0; j < 8; ++j) tile[s][dc + j] = v[j];
    }
    __syncthreads();
#pragma unroll
    for (int p = 0; p < 2; ++p) {
      int d = p * 32 + (tid >> 3), sc = (tid & 7) * 8;
      bf16x4 a, bb;
#pragma unroll
      for (int j = 0; j < 4; ++j) a[j] = tile[sc + j][d];
#pragma unroll
      for (int j = 0; j < 4; ++j) bb[j] = tile[sc + 4 + j][d];
      int q1 = sc & 31, q2 = q1 + 4;
      int p1 = (q1 < 16) ? (q1 >> 2) * 8 : ((q1 - 16) >> 2) * 8 + 4;
      int p2 = (q2 < 16) ? (q2 >> 2) * 8 : ((q2 - 16) >> 2) * 8 + 4;
      int s = ((d & 15) >> 1) & 3;
      p1 = ((((p1 >> 3) ^ s)) << 3) | (p1 & 7);
      p2 = ((((p2 >> 3) ^ s)) << 3) | (p2 & 7);
      size_t rowbase = ((size_t)h * DV + d0 + d) * S_LEN + s0 + (sc & ~31);
      *(bf16x4*)(vtg + rowbase + p1) = a;
      *(bf16x4*)(vtg + rowbase + p2) = bb;
    }
  }
}

// ---------------- fused flash attention v10 (proven 160us config, unchanged) ----------------
__global__ __launch_bounds__(256, 2) void attn10(const short* __restrict__ q,
                                                 const short* __restrict__ kc,
                                                 const short* __restrict__ vtg,
                                                 short* __restrict__ out) {
  __shared__ alignas(16) short ks[2][32 * 256];  // 32KB, 512B rows, 3-bit src XOR
  __shared__ alignas(16) short vt[2][256 * 32];  // 32KB, vt[d][key-perm], 64B rows
  int bid = blockIdx.x;
  int swz = (bid & 7) * 40 + (bid >> 3);         // 320 = 8*40, bijective
  int h = swz >> 4, qblk = swz & 15;
  int tid = threadIdx.x;
  int w = tid >> 6, l = tid & 63;
  int lr = l & 15, lg = l >> 4;

  const char* kch = (const char*)(kc + (size_t)h * S_LEN * HD);
  const short* vth = vtg + (size_t)h * DV * S_LEN;

  int qrowA = qblk * 128 + w * 32 + lr;
  const short* qbA = q + (size_t)qrowA * Q_N + h * HD;
  const short* qbB = qbA + (size_t)16 * Q_N;
  bf16x8 qfA[8], qfB[8];
#pragma unroll
  for (int kk = 0; kk < 8; ++kk) {
    bf16x8 va = *(const bf16x8*)(qbA + kk * 32 + lg * 8);
    bf16x8 vb = *(const bf16x8*)(qbB + kk * 32 + lg * 8);
#pragma unroll
    for (int j = 0; j < 8; ++j) {
      va[j] = f2bs(bs2f(va[j]) * 0.0625f);
      vb[j] = f2bs(bs2f(vb[j]) * 0.0625f);
    }
    qfA[kk] = va;
    qfB[kk] = vb;
  }

  f32x4 accA[16] = {}, accB[16] = {};
  float mA = -3e38f, mB = -3e38f;
  float lsA = 0.f, lsB = 0.f;

  auto stage_k = [&](int buf, int key0) {
#pragma unroll
    for (int p = 0; p < 4; ++p) {
      int c = p * 256 + tid;
      int row = c >> 5;
      int sb = ((c & 31) * 16) ^ ((row & 7) << 4);
      gload16(kch + (size_t)(key0 + row) * 512 + sb, (char*)ks[buf] + c * 16);
    }
  };
  auto stage_v = [&](int buf, int key0) {
#pragma unroll
    for (int p = 0; p < 4; ++p) {
      int c = p * 256 + tid;
      int d = c >> 2, slot = c & 3;
      gload16(vth + (size_t)d * S_LEN + key0 + slot * 8, (char*)vt[buf] + c * 16);
    }
  };

  stage_k(0, 0);
  stage_v(0, 0);
  WAIT_VM0();
  __builtin_amdgcn_s_barrier();

  int sxor = (lr >> 1) & 3;

  for (int kb = 0; kb < S_LEN / 32; ++kb) {
    int cur = kb & 1;
    int key0 = kb * 32;
    if (kb + 1 < S_LEN / 32) {
      stage_k(cur ^ 1, key0 + 32);
      stage_v(cur ^ 1, key0 + 32);
    }

    f32x4 s0A = {}, s1A = {}, s0B = {}, s1B = {};
    __builtin_amdgcn_s_setprio(1);
#pragma unroll
    for (int kk = 0; kk < 8; ++kk) {
      int cb = kk * 64 + lg * 16;
      int sw = (lr & 7) << 4;
      bf16x8 k0 = *(const bf16x8*)((const char*)ks[cur] + lr * 512 + (cb ^ sw));
      bf16x8 k1 = *(const bf16x8*)((const char*)ks[cur] + (16 + lr) * 512 + (cb ^ sw));
      s0A = __builtin_amdgcn_mfma_f32_16x16x32_bf16(k0, qfA[kk], s0A, 0, 0, 0);
      s1A = __builtin_amdgcn_mfma_f32_16x16x32_bf16(k1, qfA[kk], s1A, 0, 0, 0);
      s0B = __builtin_amdgcn_mfma_f32_16x16x32_bf16(k0, qfB[kk], s0B, 0, 0, 0);
      s1B = __builtin_amdgcn_mfma_f32_16x16x32_bf16(k1, qfB[kk], s1B, 0, 0, 0);
    }
    __builtin_amdgcn_s_setprio(0);

    bf16x8 paA, paB;
    {
      float mx = fmaxf(fmaxf(fmaxf(s0A[0], s0A[1]), fmaxf(s0A[2], s0A[3])),
                       fmaxf(fmaxf(s1A[0], s1A[1]), fmaxf(s1A[2], s1A[3])));
      mx = fmaxf(mx, __shfl_xor(mx, 16));
      mx = fmaxf(mx, __shfl_xor(mx, 32));
      bool grow = mx > mA + 8.f;
      if (__any((int)grow)) {
        float mn = fmaxf(mA, mx);
        float co = __expf(mA - mn);
        mA = mn;
        lsA *= co;
        float c0 = __shfl(co, (l & 48) | (lg * 4 + 0));
        float c1 = __shfl(co, (l & 48) | (lg * 4 + 1));
        float c2 = __shfl(co, (l & 48) | (lg * 4 + 2));
        float c3 = __shfl(co, (l & 48) | (lg * 4 + 3));
#pragma unroll
        for (int t = 0; t < 16; ++t) {
          accA[t][0] *= c0; accA[t][1] *= c1; accA[t][2] *= c2; accA[t][3] *= c3;
        }
      }
      float e0 = __expf(s0A[0] - mA), e1 = __expf(s0A[1] - mA);
      float e2 = __expf(s0A[2] - mA), e3 = __expf(s0A[3] - mA);
      float e4 = __expf(s1A[0] - mA), e5 = __expf(s1A[1] - mA);
      float e6 = __expf(s1A[2] - mA), e7 = __expf(s1A[3] - mA);
      float ts = ((e0 + e1) + (e2 + e3)) + ((e4 + e5) + (e6 + e7));
      ts += __shfl_xor(ts, 16);
      ts += __shfl_xor(ts, 32);
      lsA += ts;
      paA[0] = f2bs(e0); paA[1] = f2bs(e1); paA[2] = f2bs(e2); paA[3] = f2bs(e3);
      paA[4] = f2bs(e4); paA[5] = f2bs(e5); paA[6] = f2bs(e6); paA[7] = f2bs(e7);
    }
    {
      float mx = fmaxf(fmaxf(fmaxf(s0B[0], s0B[1]), fmaxf(s0B[2], s0B[3])),
                       fmaxf(fmaxf(s1B[0], s1B[1]), fmaxf(s1B[2], s1B[3])));
      mx = fmaxf(mx, __shfl_xor(mx, 16));
      mx = fmaxf(mx, __shfl_xor(mx, 32));
      bool grow = mx > mB + 8.f;
      if (__any((int)grow)) {
        float mn = fmaxf(mB, mx);
        float co = __expf(mB - mn);
        mB = mn;
        lsB *= co;
        float c0 = __shfl(co, (l & 48) | (lg * 4 + 0));
        float c1 = __shfl(co, (l & 48) | (lg * 4 + 1));
        float c2 = __shfl(co, (l & 48) | (lg * 4 + 2));
        float c3 = __shfl(co, (l & 48) | (lg * 4 + 3));
#pragma unroll
        for (int t = 0; t < 16; ++t) {
          accB[t][0] *= c0; accB[t][1] *= c1; accB[t][2] *= c2; accB[t][3] *= c3;
        }
      }
      float e0 = __expf(s0B[0] - mB), e1 = __expf(s0B[1] - mB);
      float e2 = __expf(s0B[2] - mB), e3 = __expf(s0B[3] - mB);
      float e4 = __expf(s1B[0] - mB), e5 = __expf(s1B[1] - mB);
      float e6 = __expf(s1B[2] - mB), e7 = __expf(s1B[3] - mB);
      float ts = ((e0 + e1) + (e2 + e3)) + ((e4 + e5) + (e6 + e7));
      ts += __shfl_xor(ts, 16);
      ts += __shfl_xor(ts, 32);
      lsB += ts;
      paB[0] = f2bs(e0); paB[1] = f2bs(e1); paB[2] = f2bs(e2); paB[3] = f2bs(e3);
      paB[4] = f2bs(e4); paB[5] = f2bs(e5); paB[6] = f2bs(e6); paB[7] = f2bs(e7);
    }

    __builtin_amdgcn_s_setprio(1);
#pragma unroll
    for (int t = 0; t < 16; ++t) {
      int d = t * 16 + lr;
      bf16x8 vf = *(const bf16x8*)((const char*)vt[cur] + d * 64 + ((lg ^ sxor) << 4));
      accA[t] = __builtin_amdgcn_mfma_f32_16x16x32_bf16(paA, vf, accA[t], 0, 0, 0);
      accB[t] = __builtin_amdgcn_mfma_f32_16x16x32_bf16(paB, vf, accB[t], 0, 0, 0);
    }
    __builtin_amdgcn_s_setprio(0);

    WAIT_VM0();
    __builtin_amdgcn_s_barrier();
  }

  {
    float inv = 1.f / lsA;
    float i0 = __shfl(inv, (l & 48) | (lg * 4 + 0));
    float i1 = __shfl(inv, (l & 48) | (lg * 4 + 1));
    float i2 = __shfl(inv, (l & 48) | (lg * 4 + 2));
    float i3 = __shfl(inv, (l & 48) | (lg * 4 + 3));
#pragma unroll
    for (int t = 0; t < 16; ++t) {
      int row = qblk * 128 + w * 32 + lg * 4;
      int col = h * DV + t * 16 + lr;
      out[(size_t)(row + 0) * O_N + col] = f2bs(accA[t][0] * i0);
      out[(size_t)(row + 1) * O_N + col] = f2bs(accA[t][1] * i1);
      out[(size_t)(row + 2) * O_N + col] = f2bs(accA[t][2] * i2);
      out[(size_t)(row + 3) * O_N + col] = f2bs(accA[t][3] * i3);
    }
  }
  {
    float inv = 1.f / lsB;
    float i0 = __shfl(inv, (l & 48) | (lg * 4 + 0));
    float i1 = __shfl(inv, (l & 48) | (lg * 4 + 1));
    float i2 = __shfl(inv, (l & 48) | (lg * 4 + 2));
    float i3 = __shfl(inv, (l & 48) | (lg * 4 + 3));
#pragma unroll
    for (int t = 0; t < 16; ++t) {
      int row = qblk * 128 + w * 32 + 16 + lg * 4;
      int col = h * DV + t * 16 + lr;
      out[(size_t)(row + 0) * O_N + col] = f2bs(accB[t][0] * i0);
      out[(size_t)(row + 1) * O_N + col] = f2bs(accB[t][1] * i1);
      out[(size_t)(row + 2) * O_N + col] = f2bs(accB[t][2] * i2);
      out[(size_t)(row + 3) * O_N + col] = f2bs(accB[t][3] * i3);
    }
  }
}

extern "C" void kernel_launch(void* const* d_in, const int* in_sizes, int n_in,
                              void* d_out, int out_size, void* d_ws, size_t ws_size,
                              hipStream_t stream) {
  const float* x       = (const float*)d_in[0];
  const int*   pos     = (const int*)d_in[1];
  const float* q_a_w   = (const float*)d_in[2];
  const float* q_b_w   = (const float*)d_in[3];
  const float* kv_a_w  = (const float*)d_in[4];
  const float* kv_b_w  = (const float*)d_in[5];
  const float* o_w     = (const float*)d_in[6];
  const float* q_a_ln  = (const float*)d_in[7];
  const float* kv_a_ln = (const float*)d_in[8];
  float* out = (float*)d_out;

  char* p = (char*)d_ws;
  auto alloc = [&](size_t bytes) {
    char* r = p;
    p += (bytes + 255) & ~(size_t)255;
    return r;
  };
  short* xb    = (short*)alloc((size_t)S_LEN * HID * 2);
  short* wcat  = (short*)alloc((size_t)QKVA * HID * 2);
  short* qbw   = (short*)alloc((size_t)Q_N * QR * 2);
  short* kvbw  = (short*)alloc((size_t)KV_N * KVR * 2);
  short* ow    = (short*)alloc((size_t)HID * O_N * 2);
  float* qkv   = (float*)alloc((size_t)S_LEN * QKVA * 4);
  short* q_ln  = (short*)alloc((size_t)S_LEN * QR * 2);
  short* qbuf  = (short*)alloc((size_t)S_LEN * Q_N * 2);
  short* kv_ln = (short*)alloc((size_t)S_LEN * KVR * 2);
  short* kvx   = (short*)alloc((size_t)S_LEN * KV_N * 2);
  short* kr    = (short*)alloc((size_t)S_LEN * 64 * 2);
  float* ct    = (float*)alloc((size_t)S_LEN * 32 * 4);
  float* st    = (float*)alloc((size_t)S_LEN * 32 * 4);
  short* ao    = (short*)alloc((size_t)S_LEN * O_N * 2);
  short* kcb   = (short*)alloc((size_t)NH * S_LEN * HD * 2);
  short* vtg   = (short*)alloc((size_t)NH * DV * S_LEN * 2);
  (void)ws_size; (void)n_in; (void)in_sizes; (void)out_size;

  dim3 blk(256);
  f2b_multi<<<dim3(2048), blk, 0, stream>>>(x, q_a_w, kv_a_w, q_b_w, kv_b_w, o_w,
                                            xb, wcat, wcat + (size_t)QR * HID,
                                            qbw, kvbw, ow);
  (void)hipMemsetAsync(wcat + (size_t)(QR + KVA_N) * HID, 0,
                       (size_t)(KVAP - KVA_N) * HID * 2, stream);

  gemm64<<<dim3(QKVA / 128, S_LEN / 64), blk, 0, stream>>>(xb, wcat, qkv, S_LEN, QKVA, HID);
  rmsnorm2_kernel<<<dim3(S_LEN), blk, 0, stream>>>(qkv, q_a_ln, kv_a_ln, q_ln, kv_ln);
  // fused up-projections: q_b (640 blocks) + kv_b (1120 blocks) in ONE dispatch
  gemm128_dual<<<dim3(1760), blk, 0, stream>>>(q_ln, qbw, qbuf, kv_ln, kvbw, kvx);
  rope_table_kernel<<<dim3(S_LEN / 256), blk, 0, stream>>>(pos, ct, st);
  rope_fused_kernel<<<dim3(168), blk, 0, stream>>>(qbuf, qkv, ct, st, kr);
  kv_prep<<<dim3(7680), blk, 0, stream>>>(kvx, kr, kcb, vtg);
  attn10<<<dim3(NH * S_LEN / 128), blk, 0, stream>>>(qbuf, kcb, vtg, ao);
  // output projection back on gemm64 (512 blocks = 2/CU; gemm128 @1/CU was SLOWER, R18)
  gemm64<<<dim3(HID / 128, S_LEN / 64), blk, 0, stream>>>(ao, ow, out, S_LEN, HID, O_N);
}